// Round 1
// 369.804 us; speedup vs baseline: 1.0180x; 1.0180x over previous
//
#include <hip/hip_runtime.h>

// Problem constants
#define NB    16384   // batch
#define DIN   512     // dense in
#define NSP   26      // sparse embeddings
#define EMBD  128     // embedding dim
#define NOUT  512     // output dim
#define NI_   27      // NSP + 1
#define NTRI  378     // NI*(NI+1)/2
#define DOTK  890     // NTRI + DIN
#define KPAD  896     // DOTK padded to multiple of 64

typedef __attribute__((ext_vector_type(8)))  short bf16x8;  // 8 bf16 = 4 VGPRs
typedef __attribute__((ext_vector_type(4)))  float f32x4;   // MFMA 16x16 acc

// fp32 -> bf16 (RNE), bit-level
__device__ __forceinline__ short f2bf(float f) {
    unsigned u = __builtin_bit_cast(unsigned, f);
    unsigned r = (u + 0x7FFFu + ((u >> 16) & 1u)) >> 16;
    return (short)r;
}

__device__ __forceinline__ bf16x8 cvt8(float4 a, float4 b) {
    bf16x8 r;
    r[0] = f2bf(a.x); r[1] = f2bf(a.y); r[2] = f2bf(a.z); r[3] = f2bf(a.w);
    r[4] = f2bf(b.x); r[5] = f2bf(b.y); r[6] = f2bf(b.z); r[7] = f2bf(b.w);
    return r;
}

// async global -> LDS, 16 B per lane; lds dst is wave-uniform base (+lane*16 by HW)
__device__ __forceinline__ void gld_lds16(const void* g, void* l) {
    __builtin_amdgcn_global_load_lds((const __attribute__((address_space(1))) void*)g,
                                     (__attribute__((address_space(3))) void*)l,
                                     16, 0, 0);
}

// ---------------------------------------------------------------------------
// Merged prep, all paths 8-wide (16B stores):
//   dense fp32 -> bf16 into zfb[:,0:512]; Wo -> bf16 padded (512x896); Wp -> bf16.
// ws re-poisoned each call -> must rerun.
// ---------------------------------------------------------------------------
#define CONV_N2  (NB * 64)            // 8-float groups of dense (1,048,576)
#define WOP_N2   (NOUT * (KPAD / 8))  // 512*112 = 57,344
#define WPB_N2   (EMBD * DIN / 8)     // 8,192
__global__ __launch_bounds__(256) void prep_all_k(const float* __restrict__ dense,
                                                  const float* __restrict__ Wo,
                                                  const float* __restrict__ Wp,
                                                  short* __restrict__ zfb,
                                                  short* __restrict__ wop,
                                                  short* __restrict__ wpb) {
    int idx = blockIdx.x * 256 + threadIdx.x;
    if (idx < CONV_N2) {
        int b = idx >> 6, c = (idx & 63) * 8;
        const float4* p = (const float4*)(dense + (size_t)b * DIN + c);
        *(bf16x8*)(zfb + (size_t)b * KPAD + c) = cvt8(p[0], p[1]);
    } else if (idx < CONV_N2 + WOP_N2) {
        int j = idx - CONV_N2;
        int o = j / (KPAD / 8), rem = j - o * (KPAD / 8);
        int k = rem * 8;
        const float* src = Wo + (size_t)o * DOTK + k;
        bf16x8 r;
#pragma unroll
        for (int t = 0; t < 8; ++t) r[t] = (k + t < DOTK) ? f2bf(src[t]) : (short)0;
        *(bf16x8*)(wop + (size_t)o * KPAD + k) = r;
    } else {
        int j = idx - CONV_N2 - WOP_N2;
        if (j < WPB_N2) {
            const float4* p = (const float4*)(Wp + (size_t)j * 8);
            *(bf16x8*)(wpb + (size_t)j * 8) = cvt8(p[0], p[1]);
        }
    }
}

// ---------------------------------------------------------------------------
// bf16 NT-GEMM via MFMA 16x16x32, BK=64: C[MxN] = A[Mxlda].rows(B[Nxldb]) + bias
// Block: 256 threads = 4 waves (2x2), each wave (BM/2 x BN/2).
// Staging: global_load_lds width=16. LDS rows = 64 shorts (128B = 8 16B-segs),
// XOR swizzle: physical seg = logical seg ^ (row&7). DMA writes lane->lane*16
// (conflict-free by construction); b128 read phases of 8 lanes hit 8 distinct
// segs -> conflict-free. Requires M%BM==0, N%BN==0, K%64==0, total blocks %8==0.
// GXL2 = log2(gridDim.x) (compile-time, enables XCD swizzle with shifts only).
// XCD swizzle: XCD k gets nwg/8 consecutive tiles -> A-panel reuse lands in
// one XCD's L2 instead of being re-fetched by 2-4 XCDs.
// ---------------------------------------------------------------------------
template <int BM, int BN, bool OUTBF, int GXL2>
__global__ __launch_bounds__(256) void gemm_mfma(const short* __restrict__ A, int lda,
                                                 const short* __restrict__ Bm, int ldb,
                                                 const float* __restrict__ bias,
                                                 void* __restrict__ Cp, int ldc, int K) {
    constexpr int WM = BM / 2, WN = BN / 2;
    constexpr int MT = WM / 16, NT = WN / 16;
    __shared__ short As[BM * 64];
    __shared__ short Bs[BN * 64];

    const int tid = threadIdx.x;
    const int w = tid >> 6, l = tid & 63;
    const int wm = w >> 1, wn = w & 1;
    const int r0 = l & 15, q = l >> 4;

    // XCD-aware bijective swizzle (nwg % 8 == 0 guaranteed by launch config)
    const int nwg = (int)(gridDim.y << GXL2);
    const int bid = ((int)blockIdx.y << GXL2) | (int)blockIdx.x;
    const int swz = (bid & 7) * (nwg >> 3) + (bid >> 3);
    const int m0 = (swz >> GXL2) * BM;
    const int n0 = (swz & ((1 << GXL2) - 1)) * BN;

    // staging lane mapping: 8 rows x 8 segs per wave-instruction (1 KB)
    const int lr = l >> 3, pseg = l & 7;

    const f32x4 zero4 = {0.f, 0.f, 0.f, 0.f};
    f32x4 acc[MT][NT];
#pragma unroll
    for (int mi = 0; mi < MT; ++mi)
#pragma unroll
        for (int ni = 0; ni < NT; ++ni) acc[mi][ni] = zero4;

    for (int k0 = 0; k0 < K; k0 += 64) {
        // stage tile: wave w covers rows [w*(BM/4), ...), 8 rows per inst
#pragma unroll
        for (int i = 0; i < BM / 32; ++i) {
            int r = w * (BM / 4) + i * 8 + lr;           // global tile row
            int ls = pseg ^ (r & 7);                     // logical seg to fetch
            gld_lds16(A + (size_t)(m0 + r) * lda + k0 + ls * 8,
                      (char*)As + (w * (BM / 4) + i * 8) * 128);
        }
#pragma unroll
        for (int i = 0; i < BN / 32; ++i) {
            int r = w * (BN / 4) + i * 8 + lr;
            int ls = pseg ^ (r & 7);
            gld_lds16(Bm + (size_t)(n0 + r) * ldb + k0 + ls * 8,
                      (char*)Bs + (w * (BN / 4) + i * 8) * 128);
        }
        __syncthreads();   // vmcnt drain: tile fully in LDS

#pragma unroll
        for (int h = 0; h < 2; ++h) {                    // two K=32 halves
            bf16x8 af[MT], bfr[NT];
#pragma unroll
            for (int mi = 0; mi < MT; ++mi) {
                int r = wm * WM + mi * 16 + r0;
                af[mi] = *(const bf16x8*)&As[r * 64 + ((h * 4 + q) ^ (r & 7)) * 8];
            }
#pragma unroll
            for (int ni = 0; ni < NT; ++ni) {
                int r = wn * WN + ni * 16 + r0;
                bfr[ni] = *(const bf16x8*)&Bs[r * 64 + ((h * 4 + q) ^ (r & 7)) * 8];
            }
#pragma unroll
            for (int mi = 0; mi < MT; ++mi)
#pragma unroll
                for (int ni = 0; ni < NT; ++ni)
                    acc[mi][ni] = __builtin_amdgcn_mfma_f32_16x16x32_bf16(
                        af[mi], bfr[ni], acc[mi][ni], 0, 0, 0);
        }
        __syncthreads();   // all reads done before next-iter overwrite
    }

    // epilogue: C/D layout col=lane&15, row=(lane>>4)*4+reg  [m89/m91]
#pragma unroll
    for (int mi = 0; mi < MT; ++mi) {
#pragma unroll
        for (int ni = 0; ni < NT; ++ni) {
            int col = n0 + wn * WN + ni * 16 + r0;
            float bb = bias[col];
#pragma unroll
            for (int r = 0; r < 4; ++r) {
                int row = m0 + wm * WM + mi * 16 + q * 4 + r;
                float v = acc[mi][ni][r] + bb;
                if (OUTBF) ((short*)Cp)[(size_t)row * ldc + col] = f2bf(v);
                else       ((float*)Cp)[(size_t)row * ldc + col] = v;
            }
        }
    }
}

// ---------------------------------------------------------------------------
// Interaction via MFMA: one wave per batch row. T = [dproj ; sparse] (27x128,
// zero-padded to 32). Gram = T.T^T with 16x16x32 MFMA; tril -> zfb[512:890] bf16,
// cols [890:896) zeroed. Skips the col>row tile. Wave-private LDS row ->
// no __syncthreads needed (DS ops of one wave are in-order; compiler cannot
// reorder aliasing ds_write/ds_read).
// ---------------------------------------------------------------------------
__global__ __launch_bounds__(256) void interact_mfma(const float* __restrict__ sparse,
                                                     const short* __restrict__ dprojb,
                                                     short* __restrict__ zfb) {
    __shared__ short zt[4][384];   // 378 tril + 6 zero-pad, per wave
    const int w = threadIdx.x >> 6, l = threadIdx.x & 63;
    const int b = blockIdx.x * 4 + w;
    const int r0 = l & 15, q = l >> 4;

    const float* srow = sparse + (size_t)b * (NSP * EMBD);
    const short* dp = dprojb + (size_t)b * EMBD;

    const f32x4 zero4 = {0.f, 0.f, 0.f, 0.f};
    f32x4 acc00 = zero4, acc10 = zero4, acc11 = zero4;

#pragma unroll
    for (int kc = 0; kc < 4; ++kc) {
        int k = kc * 32 + q * 8;
        bf16x8 f0, f1;
        if (r0 == 0) {
            f0 = *(const bf16x8*)(dp + k);                  // T row 0 = dense_proj
        } else {
            const float* p = srow + (size_t)(r0 - 1) * EMBD + k;
            f0 = cvt8(*(const float4*)p, *(const float4*)(p + 4));
        }
        if (r0 <= 10) {                                     // T rows 16..26
            const float* p = srow + (size_t)(15 + r0) * EMBD + k;
            f1 = cvt8(*(const float4*)p, *(const float4*)(p + 4));
        } else {
            f1 = (bf16x8){0, 0, 0, 0, 0, 0, 0, 0};
        }
        acc00 = __builtin_amdgcn_mfma_f32_16x16x32_bf16(f0, f0, acc00, 0, 0, 0);
        acc10 = __builtin_amdgcn_mfma_f32_16x16x32_bf16(f1, f0, acc10, 0, 0, 0);
        acc11 = __builtin_amdgcn_mfma_f32_16x16x32_bf16(f1, f1, acc11, 0, 0, 0);
    }

    // scatter tril entries to LDS: row=(tile*16 + q*4 + r), col=(tile*16 + r0)
#pragma unroll
    for (int r = 0; r < 4; ++r) {
        int row, col;
        row = q * 4 + r;       col = r0;                    // tile (0,0)
        if (col <= row)             zt[w][row * (row + 1) / 2 + col] = f2bf(acc00[r]);
        row = 16 + q * 4 + r;  col = r0;                    // tile (1,0)
        if (row < NI_)              zt[w][row * (row + 1) / 2 + col] = f2bf(acc10[r]);
        /* tile (1,1) */       col = 16 + r0;
        if (row < NI_ && col <= row) zt[w][row * (row + 1) / 2 + col] = f2bf(acc11[r]);
    }
    // zero-pad tail (cols 890..895 of zfb row) and copy own row, 4B/lane
    if (l < 6) zt[w][NTRI + l] = 0;
    const int* zrow = (const int*)zt[w];
    int* dst = (int*)(zfb + (size_t)b * KPAD + DIN);
#pragma unroll
    for (int t = 0; t < 3; ++t) dst[t * 64 + l] = zrow[t * 64 + l];
}

// ---------------------------------------------------------------------------
extern "C" void kernel_launch(void* const* d_in, const int* in_sizes, int n_in,
                              void* d_out, int out_size, void* d_ws, size_t ws_size,
                              hipStream_t stream) {
    const float* dense  = (const float*)d_in[0];  // (16384, 512)
    const float* sparse = (const float*)d_in[1];  // (16384, 26, 128)
    const float* Wp     = (const float*)d_in[2];  // (128, 512)
    const float* bp     = (const float*)d_in[3];  // (128,)
    const float* Wo     = (const float*)d_in[4];  // (512, 890)
    const float* bo     = (const float*)d_in[5];  // (512,)
    float* out = (float*)d_out;                   // (16384, 512)

    short* zfb    = (short*)d_ws;                          // NB x 896 bf16
    short* dprojb = zfb + (size_t)NB * KPAD;               // NB x 128 bf16
    short* wop    = dprojb + (size_t)NB * EMBD;            // 512 x 896 bf16
    short* wpb    = wop + (size_t)NOUT * KPAD;             // 128 x 512 bf16

    // 1) all conversions in one launch (8-wide)
    prep_all_k<<<(CONV_N2 + WOP_N2 + WPB_N2 + 255) / 256, 256, 0, stream>>>(
        dense, Wo, Wp, zfb, wop, wpb);

    // 2) dproj = dense @ Wp.T + bp  (M=16384, N=128, K=512), bf16 out
    //    64x64 tiles -> 512 blocks (2/CU) for latency hiding; GXL2=1
    gemm_mfma<64, 64, true, 1><<<dim3(EMBD / 64, NB / 64), 256, 0, stream>>>(
        zfb, KPAD, wpb, DIN, bp, dprojb, EMBD, DIN);

    // 3) per-row Gram -> zfb[:, 512:896]
    interact_mfma<<<NB / 4, 256, 0, stream>>>(sparse, dprojb, zfb);

    // 4) out = Zflat @ Wo.T + bo  (M=16384, N=512, K=896), fp32 out; GXL2=2
    gemm_mfma<128, 128, false, 2><<<dim3(NOUT / 128, NB / 128), 256, 0, stream>>>(
        zfb, KPAD, wop, KPAD, bo, out, NOUT, KPAD);
}